// Round 1
// baseline (207.413 us; speedup 1.0000x reference)
//
#include <hip/hip_runtime.h>

#define W 320
#define H 96
#define FS 96
#define BS 8
#define NPLANES 9      // 1 + 2*4 levels
#define CH 16          // channels staged per LDS stage
#define NSTAGES 6      // FS / CH
#define CW 160         // columns per block (W/2) -> 2 chunks per row
#define HALO 4
#define SROW 168       // HALO + CW + HALO floats per channel (42 float4 quads)
#define QPC 42         // quads per channel row
#define NTHREADS 128   // 2 waves; 80 active in compute (VX=2 over CW=160)

__global__ __launch_bounds__(NTHREADS, 3)
void cost_volume_kernel(const float* __restrict__ f1,
                        const float* __restrict__ f2,
                        float* __restrict__ out)
{
    // single buffer: 16 * 168 * 4 = 10,752 B  (occupancy is grid-capped, not LDS-capped)
    __shared__ __align__(16) float sh[CH * SROW];

    const int t     = threadIdx.x;
    const int idx   = blockIdx.x;
    const int chunk = idx & 1;            // 0 | 1  -> xb = 0 | 160
    const int row   = idx >> 1;           // 0..767 = (b, y)
    const int b     = row / H;
    const int y     = row % H;
    const int xb    = chunk * CW;

    const size_t rowoff = ((size_t)(b * FS) * H + y) * W;
    const float* f1row = f1 + rowoff;     // + c*H*W per channel
    const float* f2row = f2 + rowoff;

    // staging map: thread owns channel sc = t>>3, sub-lane su = t&7,
    // quads q = su + 8k, k=0..5 (q<42). Quad q covers global cols xb-4+4q .. +3;
    // halo is quad-aligned so OOB handling is a per-quad exec-masked predicate.
    const int sc = t >> 3;
    const int su = t & 7;

    float4 r[6];

    auto issue = [&](int c0) {
        const float* f2c = f2row + (size_t)(c0 + sc) * (H * W);
#pragma unroll
        for (int k = 0; k < 6; ++k) {
            const int q   = su + 8 * k;
            const int col = xb - HALO + 4 * q;       // multiple of 4
            float4 v = make_float4(0.f, 0.f, 0.f, 0.f);
            if (q < QPC && (unsigned)col < W)        // exec-masked: no OOB access
                v = *(const float4*)(f2c + col);
            r[k] = v;
        }
    };

    // prologue: stage-0 loads in flight while we init accumulators
    issue(0);

    float acc0[NPLANES], acc1[NPLANES];
#pragma unroll
    for (int p = 0; p < NPLANES; ++p) { acc0[p] = 0.f; acc1[p] = 0.f; }

    const int xi = t;          // compute lane: xi < 80
    const int x0 = 2 * xi;     // local column, even -> 8B-aligned reads

    for (int s = 0; s < NSTAGES; ++s) {
        const int c0 = s * CH;

        // B1: (a) all waves done reading stage s-1; (b) the implicit vmcnt(0)
        // drain is exactly the wait for our stage-s prefetch -> no wasted drain.
        __syncthreads();

#pragma unroll
        for (int k = 0; k < 6; ++k) {
            const int q = su + 8 * k;
            if (q < QPC)
                *(float4*)(&sh[sc * SROW + 4 * q]) = r[k];
        }

        __syncthreads();   // B2: writes visible; nothing in flight -> free drain

        // prefetch next stage's f2 into regs: flies across the whole compute phase
        if (s + 1 < NSTAGES) issue(c0 + CH);

        if (xi < 80) {
            // hoist all 16 f1 loads -> one latency exposure per stage, not four
            float2 a[CH];
#pragma unroll
            for (int c = 0; c < CH; ++c)
                a[c] = *(const float2*)(f1row + (size_t)(c0 + c) * (H * W) + xb + x0);

#pragma unroll
            for (int c = 0; c < CH; ++c) {
                // wv[j] = f2[xb + x0 - 4 + j], j=0..9 (halo-padded via staged guards)
                float wv[10];
#pragma unroll
                for (int k = 0; k < 5; ++k) {
                    const float2 v = *(const float2*)(&sh[c * SROW + x0 + 2 * k]);
                    wv[2 * k]     = v.x;
                    wv[2 * k + 1] = v.y;
                }
                // plane p <-> shift i = p-4; f2 col = x - i = x + 4 - p
#pragma unroll
                for (int p = 0; p < NPLANES; ++p) {
                    acc0[p] = fmaf(a[c].x, wv[8 - p], acc0[p]);
                    acc1[p] = fmaf(a[c].y, wv[9 - p], acc1[p]);
                }
            }
        }
    }

    if (xi < 80) {
        const float scale = 1.0f / (float)FS;
#pragma unroll
        for (int p = 0; p < NPLANES; ++p) {
            float2 o;
            o.x = acc0[p] * scale;
            o.y = acc1[p] * scale;
            *(float2*)(out + (((size_t)(b * NPLANES + p)) * H + y) * W + xb + x0) = o;
        }
    }
}

extern "C" void kernel_launch(void* const* d_in, const int* in_sizes, int n_in,
                              void* d_out, int out_size, void* d_ws, size_t ws_size,
                              hipStream_t stream) {
    (void)in_sizes; (void)n_in; (void)d_ws; (void)ws_size; (void)out_size;
    const float* f1 = (const float*)d_in[0];
    const float* f2 = (const float*)d_in[1];
    float* out = (float*)d_out;

    dim3 grid(BS * H * 2);    // 1536 blocks = 6 per CU (was grid-capped at 3)
    dim3 block(NTHREADS);
    cost_volume_kernel<<<grid, block, 0, stream>>>(f1, f2, out);
}